// Round 13
// baseline (260.227 us; speedup 1.0000x reference)
//
#include <hip/hip_runtime.h>
#include <hip/hip_bf16.h>
#include <math.h>

#define B_ 16
#define S_ 1024
#define D_ 256
#define H_ 8
#define L_ 4
#define DH_ 32
#define OBS_ 160
#define ACT_ 96
#define M_ (B_*S_)   // 16384

typedef __attribute__((ext_vector_type(8)))  short short8v;   // 8 bf16
typedef __attribute__((ext_vector_type(4)))  short short4v;   // 4 bf16
typedef __attribute__((ext_vector_type(4)))  float f32x4;
typedef __attribute__((ext_vector_type(4)))  unsigned uint4v;

#define ALPHA_ 0.25507313f   // log2(e)/sqrt(32)

__device__ inline short bf16rne(float x) {
    unsigned u = __builtin_bit_cast(unsigned, x);
    unsigned r = (u + 0x7fffu + ((u >> 16) & 1u)) >> 16;
    return (short)r;
}

#if __has_builtin(__builtin_amdgcn_exp2f)
#define EXP2F(x) __builtin_amdgcn_exp2f(x)
#else
#define EXP2F(x) exp2f(x)
#endif

__device__ inline unsigned cvtpk_bf16(float lo, float hi) {
    unsigned r;
    asm("v_cvt_pk_bf16_f32 %0, %1, %2" : "=v"(r) : "v"(lo), "v"(hi));
    return r;
}

// ------------------------------------------------------------ fused preproc
// blocks [0,288): weight cvt+transpose (18 matrices x 16 tiles)
// blocks [288,2336): input concat+cvt (2048)
// blocks [2336,2400): rope table (64)
__global__ __launch_bounds__(256) void preproc_k(
    const float* __restrict__ obs, const float* __restrict__ act,
    const float* __restrict__ qW, const float* __restrict__ kW,
    const float* __restrict__ vW, const float* __restrict__ oW,
    const float* __restrict__ outW, const float* __restrict__ inW,
    short* __restrict__ xIn,
    short* __restrict__ WTqkv, short* __restrict__ WTo,
    short* __restrict__ WTf, short* __restrict__ WTin,
    float* __restrict__ cosT2, float* __restrict__ sinT2)
{
    __shared__ float T[64][65];
    const int bid = blockIdx.x;
    const int tid = threadIdx.x;

    if (bid < 288) {
        const int bx = bid & 15, z = bid >> 4;   // z = 0..17
        const int tr = (bx & 3) * 64, tc = (bx >> 2) * 64;
        const float* src;
        short* dst;
        if (z < 16) {
            int lay = z >> 2, w = z & 3;
            if (w == 0)      { src = qW + lay * 65536; dst = WTqkv + lay * 196608; }
            else if (w == 1) { src = kW + lay * 65536; dst = WTqkv + lay * 196608 + 65536; }
            else if (w == 2) { src = vW + lay * 65536; dst = WTqkv + lay * 196608 + 131072; }
            else             { src = oW + lay * 65536; dst = WTo + lay * 65536; }
        } else if (z == 16) { src = outW; dst = WTf; }
        else                { src = inW;  dst = WTin; }
        #pragma unroll
        for (int it = 0; it < 4; ++it) {
            int r = (tid >> 4) + it * 16, c = (tid & 15) * 4;
            *(float4*)&T[r][c] = *(const float4*)&src[(size_t)(tr + r) * 256 + tc + c];
        }
        __syncthreads();
        #pragma unroll
        for (int it = 0; it < 4; ++it) {
            int n = (tid >> 4) + it * 16, k = (tid & 15) * 4;
            short4v o = {bf16rne(T[k][n]), bf16rne(T[k + 1][n]),
                         bf16rne(T[k + 2][n]), bf16rne(T[k + 3][n])};
            *(short4v*)&dst[(size_t)(tc + n) * 256 + tr + k] = o;
        }
    } else if (bid < 2336) {
        const int idx = ((bid - 288) * 256 + tid) * 8;
        const int row = idx >> 8, col = idx & 255;
        const float* s = (col < OBS_) ? (obs + (size_t)row * OBS_ + col)
                                      : (act + (size_t)row * ACT_ + (col - OBS_));
        const float4 v0 = *(const float4*)s;
        const float4 v1 = *(const float4*)(s + 4);
        short8v o = {bf16rne(v0.x), bf16rne(v0.y), bf16rne(v0.z), bf16rne(v0.w),
                     bf16rne(v1.x), bf16rne(v1.y), bf16rne(v1.z), bf16rne(v1.w)};
        *(short8v*)&xIn[idx] = o;
    } else {
        const int idx = (bid - 2336) * 256 + tid;   // 16384
        const int i = idx >> 10, s = idx & 1023;
        float invf = powf(10000.0f, -(float)(2 * i) / 32.0f);
        float ang = (float)s * invf;
        float sn, cs;
        sincosf(ang, &sn, &cs);
        cosT2[idx] = cs;
        sinT2[idx] = sn;
    }
}

// ------------------------------------------------------------ MFMA GEMM
// BM = IB*64 (IB=4: 256 rows for QKV; IB=2: 128 rows for N=256 GEMMs).
// BN=64, BK=32, 8 waves, reg-staged double-buffered LDS.
// Grid = (rows, cols): row-panel blocks share an XCD.
// EPI 0 (IB=4): QKV fused (N=768): Q -> *ALPHA,rope -> (B,H,DH,S) direct;
//        K -> rope -> (B,H,S,DH) via LDS bounce; V -> (B,H,DH,S) sigma-keys.
// EPI 1: + residual xF -> xF(f32) + xB(bf16)
// EPI 2: -> xF + xB
template<int EPI, int IB>
__global__ __launch_bounds__(512, 4) void gemm_k(
    const short* __restrict__ A, const short* __restrict__ WT,
    const float* __restrict__ bq, const float* __restrict__ bk,
    const float* __restrict__ bv,
    float* __restrict__ xF, short* __restrict__ xB,
    short* __restrict__ Q2, short* __restrict__ K2, short* __restrict__ VT,
    const float* __restrict__ cosT2, const float* __restrict__ sinT2)
{
    __shared__ short As[2][256 * 32];
    __shared__ short Bs[2][64 * 32];
    const int tid = threadIdx.x;          // 0..511
    const int l = tid & 63;
    const int wid = tid >> 6;             // 0..7
    const int wr = wid >> 1, wc = wid & 1;
    const int bm = blockIdx.x * (IB * 64), bn = blockIdx.y * 64;

    const short* aSrc0 = A + (size_t)(bm + (tid >> 2)) * 256 + (tid & 3) * 8;
    const short* aSrc1 = aSrc0 + 128 * 256;
    const short* bSrc  = WT + (size_t)(bn + ((tid & 255) >> 2)) * 256 + (tid & 3) * 8;

    {
        short8v a0 = *(const short8v*)aSrc0;
        *(short8v*)&As[0][tid * 8] = a0;
        if (IB == 4) {
            short8v a1 = *(const short8v*)aSrc1;
            *(short8v*)&As[0][(tid + 512) * 8] = a1;
        }
        if (tid < 256) {
            short8v b0 = *(const short8v*)bSrc;
            *(short8v*)&Bs[0][tid * 8] = b0;
        }
    }
    __syncthreads();

    f32x4 acc[IB][2];
    #pragma unroll
    for (int i = 0; i < IB; ++i)
        #pragma unroll
        for (int j = 0; j < 2; ++j) acc[i][j] = (f32x4){0.f, 0.f, 0.f, 0.f};

    #pragma unroll
    for (int t = 0; t < 8; ++t) {
        const int cur = t & 1;
        short8v na0, na1, nb;
        if (t < 7) {                    // issue next-tile loads before MFMA
            const int k = (t + 1) * 32;
            na0 = *(const short8v*)&aSrc0[k];
            if (IB == 4) na1 = *(const short8v*)&aSrc1[k];
            if (tid < 256) nb = *(const short8v*)&bSrc[k];
        }
        short8v af[IB], bf[2];
        #pragma unroll
        for (int i = 0; i < IB; ++i)
            af[i] = *(const short8v*)&As[cur][(wr * (IB * 16) + i * 16 + (l & 15)) * 32 + (l >> 4) * 8];
        #pragma unroll
        for (int j = 0; j < 2; ++j)
            bf[j] = *(const short8v*)&Bs[cur][(wc * 32 + j * 16 + (l & 15)) * 32 + (l >> 4) * 8];
        #pragma unroll
        for (int i = 0; i < IB; ++i)
            #pragma unroll
            for (int j = 0; j < 2; ++j)
                acc[i][j] = __builtin_amdgcn_mfma_f32_16x16x32_bf16(af[i], bf[j], acc[i][j], 0, 0, 0);
        if (t < 7) {
            const int nxt = cur ^ 1;
            *(short8v*)&As[nxt][tid * 8] = na0;
            if (IB == 4) *(short8v*)&As[nxt][(tid + 512) * 8] = na1;
            if (tid < 256) *(short8v*)&Bs[nxt][tid * 8] = nb;
            __syncthreads();
        }
    }

    if (EPI == 0) {
        const int region = bn >> 8;     // 0=Q 1=K 2=V (uniform per block)
        if (region != 1) {
            // Q and V: direct (B,H,DH,S) stores. V adds sigma key-perm;
            // Q adds ALPHA scale + rope.
            #pragma unroll
            for (int i = 0; i < IB; ++i) {
                const int m0 = bm + wr * (IB * 16) + i * 16 + ((l >> 4) << 2);
                const int bI = m0 >> 10, s0 = m0 & 1023;
                int sp = s0;
                if (region == 2) {
                    // sigma: key<16 -> 8*(key>>2)+(key&3); key>=16 -> +4
                    const int w = s0 & 31;
                    sp = (s0 & ~31) | ((((w & 15) >> 2) << 3) | ((w >> 4) << 2));
                }
                #pragma unroll
                for (int j = 0; j < 2; ++j) {
                    const int nl = (bn & 255) + wc * 32 + j * 16 + (l & 15);
                    const float bb = (region == 2) ? bv[nl] : bq[nl];
                    f32x4 v = acc[i][j];
                    v[0] += bb; v[1] += bb; v[2] += bb; v[3] += bb;
                    if (region == 0) {
                        v *= ALPHA_;
                        const int ir = (nl & 31) >> 1;
                        const f32x4 cs = *(const f32x4*)&cosT2[ir * 1024 + s0];
                        const f32x4 sn = *(const f32x4*)&sinT2[ir * 1024 + s0];
                        f32x4 pr;
                        #pragma unroll
                        for (int c = 0; c < 4; ++c) pr[c] = __shfl_xor(v[c], 1);
                        const float sg = (nl & 1) ? 1.f : -1.f;
                        #pragma unroll
                        for (int c = 0; c < 4; ++c)
                            v[c] = v[c] * cs[c] + sg * pr[c] * sn[c];
                    }
                    const int h = nl >> 5, dhh = nl & 31;
                    short4v o = {bf16rne(v[0]), bf16rne(v[1]),
                                 bf16rne(v[2]), bf16rne(v[3])};
                    short* dst = (region == 2) ? VT : Q2;
                    *(short4v*)&dst[((size_t)((bI * 8 + h) * 32 + dhh) << 10) + sp] = o;
                }
            }
        } else {
            // K: bias + rope, bounce via LDS -> (B,H,S,DH)
            __syncthreads();
            short* scr = &As[0][0];   // 256 x 64 bf16, chunk-XOR swizzled
            #pragma unroll
            for (int i = 0; i < IB; ++i) {
                const int tl0 = wr * (IB * 16) + i * 16 + ((l >> 4) << 2);
                const int s0r = (bm + tl0) & 1023;
                #pragma unroll
                for (int j = 0; j < 2; ++j) {
                    const int ncl = wc * 32 + j * 16 + (l & 15);
                    const int nl = (bn & 255) + ncl;
                    const float bb = bk[nl];
                    f32x4 v = acc[i][j];
                    v[0] += bb; v[1] += bb; v[2] += bb; v[3] += bb;
                    const int ir = (nl & 31) >> 1;
                    const f32x4 cs = *(const f32x4*)&cosT2[ir * 1024 + s0r];
                    const f32x4 sn = *(const f32x4*)&sinT2[ir * 1024 + s0r];
                    f32x4 pr;
                    #pragma unroll
                    for (int c = 0; c < 4; ++c) pr[c] = __shfl_xor(v[c], 1);
                    const float sg = (nl & 1) ? 1.f : -1.f;
                    #pragma unroll
                    for (int c = 0; c < 4; ++c)
                        v[c] = v[c] * cs[c] + sg * pr[c] * sn[c];
                    #pragma unroll
                    for (int c = 0; c < 4; ++c) {
                        const int tl = tl0 + c;
                        const int pos = (((ncl >> 3) ^ (tl & 7)) << 3) | (ncl & 7);
                        scr[tl * 64 + pos] = bf16rne(v[c]);
                    }
                }
            }
            __syncthreads();
            const int r = tid >> 1, h2 = tid & 1;   // r: 0..255
            const int tok = bm + r;
            const int bI = tok >> 10, s0 = tok & 1023;
            const int hh = ((bn & 255) >> 5) + h2;
            short* dst = K2 + ((size_t)((bI * 8 + hh) * 1024 + s0)) * 32;
            #pragma unroll
            for (int k = 0; k < 4; ++k) {
                const int pos = ((h2 * 4 + k) ^ (r & 7)) << 3;
                *(uint4*)&dst[k * 8] = *(const uint4*)&scr[r * 64 + pos];
            }
        }
    } else {
        #pragma unroll
        for (int i = 0; i < IB; ++i) {
            const int m0 = bm + wr * (IB * 16) + i * 16 + ((l >> 4) << 2);
            #pragma unroll
            for (int j = 0; j < 2; ++j) {
                const int nn = bn + wc * 32 + j * 16 + (l & 15);
                const float bb = bq[nn];
                const f32x4 v = acc[i][j];
                #pragma unroll
                for (int c = 0; c < 4; ++c) {
                    float rr = v[c] + bb;
                    const size_t off = (size_t)(m0 + c) * 256 + nn;
                    if (EPI == 1) rr += xF[off];
                    xF[off] = rr;
                    xB[off] = bf16rne(rr);
                }
            }
        }
    }
}

// ------------------------------------------------------------ fused out-GEMM + LayerNorm
// BM=64, BN=256 (full rows per block), grid 256 blocks, 512 threads.
// Wave tile 16 rows x 128 cols (wr2 = wid>>1 row-group, wc2 = wid&1 col-half).
// LN: per-lane partials -> 4x shfl_xor over lq -> 1KB LDS cross-wave-pair.
__global__ __launch_bounds__(512, 2) void gemmln_k(
    const short* __restrict__ A, const short* __restrict__ WT,
    const float* __restrict__ outb, const float* __restrict__ lng,
    const float* __restrict__ lnb, float* __restrict__ outp)
{
    __shared__ short As[2][64 * 32];
    __shared__ short Bs[2][256 * 32];
    __shared__ float red[64][2][2];     // [row][col-half][stat]
    const int tid = threadIdx.x;
    const int l = tid & 63;
    const int wid = tid >> 6;
    const int wr2 = wid >> 1, wc2 = wid & 1;
    const int lq = l & 15, g = l >> 4;
    const int bm = blockIdx.x * 64;

    const short* aSrc  = A + (size_t)(bm + ((tid & 255) >> 2)) * 256 + (tid & 3) * 8;
    const short* bSrc0 = WT + (size_t)(tid >> 2) * 256 + (tid & 3) * 8;
    const short* bSrc1 = bSrc0 + (size_t)128 * 256;

    if (tid < 256) *(short8v*)&As[0][tid * 8] = *(const short8v*)aSrc;
    *(short8v*)&Bs[0][tid * 8]         = *(const short8v*)bSrc0;
    *(short8v*)&Bs[0][(tid + 512) * 8] = *(const short8v*)bSrc1;
    __syncthreads();

    f32x4 acc[8];
    #pragma unroll
    for (int j = 0; j < 8; ++j) acc[j] = (f32x4){0.f, 0.f, 0.f, 0.f};

    #pragma unroll
    for (int t = 0; t < 8; ++t) {
        const int cur = t & 1;
        short8v na, nb0, nb1;
        if (t < 7) {
            const int k = (t + 1) * 32;
            if (tid < 256) na = *(const short8v*)&aSrc[k];
            nb0 = *(const short8v*)&bSrc0[k];
            nb1 = *(const short8v*)&bSrc1[k];
        }
        const short8v af = *(const short8v*)&As[cur][(wr2 * 16 + lq) * 32 + g * 8];
        short8v bf[8];
        #pragma unroll
        for (int j = 0; j < 8; ++j)
            bf[j] = *(const short8v*)&Bs[cur][(wc2 * 128 + j * 16 + lq) * 32 + g * 8];
        #pragma unroll
        for (int j = 0; j < 8; ++j)
            acc[j] = __builtin_amdgcn_mfma_f32_16x16x32_bf16(af, bf[j], acc[j], 0, 0, 0);
        if (t < 7) {
            const int nxt = cur ^ 1;
            if (tid < 256) *(short8v*)&As[nxt][tid * 8] = na;
            *(short8v*)&Bs[nxt][tid * 8]         = nb0;
            *(short8v*)&Bs[nxt][(tid + 512) * 8] = nb1;
            __syncthreads();
        }
    }

    // bias + LN partials
    float rs[4] = {0.f, 0.f, 0.f, 0.f}, rq[4] = {0.f, 0.f, 0.f, 0.f};
    #pragma unroll
    for (int j = 0; j < 8; ++j) {
        const float bb = outb[wc2 * 128 + j * 16 + lq];
        #pragma unroll
        for (int c = 0; c < 4; ++c) {
            float v = acc[j][c] + bb;
            acc[j][c] = v;
            rs[c] += v;
            rq[c] += v * v;
        }
    }
    #pragma unroll
    for (int off = 1; off <= 8; off <<= 1) {
        #pragma unroll
        for (int c = 0; c < 4; ++c) {
            rs[c] += __shfl_xor(rs[c], off);
            rq[c] += __shfl_xor(rq[c], off);
        }
    }
    if (lq == 0) {
        #pragma unroll
        for (int c = 0; c < 4; ++c) {
            red[wr2 * 16 + g * 4 + c][wc2][0] = rs[c];
            red[wr2 * 16 + g * 4 + c][wc2][1] = rq[c];
        }
    }
    __syncthreads();
    float mean[4], rstd[4];
    #pragma unroll
    for (int c = 0; c < 4; ++c) {
        const int row = wr2 * 16 + g * 4 + c;
        const float sT = red[row][0][0] + red[row][1][0];
        const float qT = red[row][0][1] + red[row][1][1];
        mean[c] = sT * (1.f / 256.f);
        const float var = qT * (1.f / 256.f) - mean[c] * mean[c];
        rstd[c] = rsqrtf(var + 1e-5f);
    }
    float* seq = outp + B_ * D_;
    #pragma unroll
    for (int j = 0; j < 8; ++j) {
        const int col = wc2 * 128 + j * 16 + lq;
        const float gv = lng[col], bvv = lnb[col];
        #pragma unroll
        for (int c = 0; c < 4; ++c) {
            const int grow = bm + wr2 * 16 + g * 4 + c;
            const float o = (acc[j][c] - mean[c]) * rstd[c] * gv + bvv;
            seq[(size_t)grow * 256 + col] = o;
            if ((grow & (S_ - 1)) == S_ - 1)
                outp[(size_t)(grow >> 10) * 256 + col] = o;
        }
    }
}

// ------------------------------------------------------------ Attention
// Q2: bf16 (B,H,DH,S) (pre-scaled by log2e/sqrt(DH), rope'd)
// K2: bf16 (B,H,S,DH) (rope'd)
// VT: bf16 (B,H,DH,S), key order sigma-permuted per 32-block
// O:  bf16 (B,S,D)
// Block = 1 head x 512 q (8 waves x 64 q). Whole K+V staged to static
// 128 KiB LDS once; ONE barrier; 32-step barrier-free loop. lsum on VALU
// (tree adds) to keep the matrix pipe at 4 MFMA/QSTEP.
__global__ __launch_bounds__(512, 2) void attn_k(
    const short* __restrict__ Q2, const short* __restrict__ K2,
    const short* __restrict__ VT, short* __restrict__ O)
{
    __shared__ short lb[65536];          // 131072 B static LDS
    const int tid = threadIdx.x;
    const int l = tid & 63, wid = tid >> 6;
    const int head = blockIdx.x & 127;   // b*8+h; bid%8 = head%8 -> XCD-pinned
    const int qh = blockIdx.x >> 7;      // 0..1
    const int q0w = qh * 512 + wid * 64;
    const int lq = l & 15, g = l >> 4;

    const short* Kh = K2 + (size_t)head * 32768;
    const short* Vh = VT + (size_t)head * 32768;

    // -------- stage all of K and V (64 KB each), swizzled tiles
    #pragma unroll
    for (int i = 0; i < 8; ++i) {
        const int c = tid + i * 512;           // 16B chunk id, 0..4095
        short8v kv = *(const short8v*)(Kh + c * 8);
        const int key = c >> 2, dc = c & 3;
        *(short8v*)((char*)lb + key * 64 + ((dc ^ ((key >> 1) & 3)) << 4)) = kv;
        short8v vv = *(const short8v*)(Vh + c * 8);
        const int dh = c >> 7, kc = c & 127;
        *(short8v*)((char*)lb + 65536 + (kc >> 2) * 2048 + dh * 64
                    + (((kc & 3) ^ ((dh >> 1) & 3)) << 4)) = vv;
    }

    // Q fragments from (B,H,DH,S): one-time strided loads
    const short* qbase = Q2 + (size_t)head * 32768 + q0w + lq;
    short8v QfA, QfB, QfC, QfD;
    #pragma unroll
    for (int j = 0; j < 8; ++j) {
        const size_t off = (size_t)(g * 8 + j) * 1024;
        QfA[j] = qbase[off];
        QfB[j] = qbase[off + 16];
        QfC[j] = qbase[off + 32];
        QfD[j] = qbase[off + 48];
    }

    const char* LBK = (const char*)lb + lq * 64 + ((g ^ ((lq >> 1) & 3)) << 4);
    const char* LBV = LBK + 65536;

    f32x4 aA0 = {0.f,0.f,0.f,0.f}, aA1 = {0.f,0.f,0.f,0.f};
    f32x4 aB0 = {0.f,0.f,0.f,0.f}, aB1 = {0.f,0.f,0.f,0.f};
    f32x4 aC0 = {0.f,0.f,0.f,0.f}, aC1 = {0.f,0.f,0.f,0.f};
    f32x4 aD0 = {0.f,0.f,0.f,0.f}, aD1 = {0.f,0.f,0.f,0.f};
    const f32x4 z4 = {0.f, 0.f, 0.f, 0.f};
    float lsA = 0.f, lsB = 0.f, lsC = 0.f, lsD = 0.f;

    __syncthreads();                      // the ONLY barrier

#define QSTEP(QF, A0, A1, LS) do {                                             \
        f32x4 s0 = __builtin_amdgcn_mfma_f32_16x16x32_bf16(Kf0, QF, z4, 0,0,0);\
        f32x4 s1 = __builtin_amdgcn_mfma_f32_16x16x32_bf16(Kf1, QF, z4, 0,0,0);\
        float p0 = EXP2F(s0[0]), p1 = EXP2F(s0[1]);                            \
        float p2 = EXP2F(s0[2]), p3 = EXP2F(s0[3]);                            \
        float p4 = EXP2F(s1[0]), p5 = EXP2F(s1[1]);                            \
        float p6 = EXP2F(s1[2]), p7 = EXP2F(s1[3]);                            \
        LS += ((p0 + p1) + (p2 + p3)) + ((p4 + p5) + (p6 + p7));               \
        uint4v pv = {cvtpk_bf16(p0, p1), cvtpk_bf16(p2, p3),                   \
                     cvtpk_bf16(p4, p5), cvtpk_bf16(p6, p7)};                  \
        short8v Pf = __builtin_bit_cast(short8v, pv);                          \
        A0 = __builtin_amdgcn_mfma_f32_16x16x32_bf16(Vf0, Pf, A0, 0,0,0);      \
        A1 = __builtin_amdgcn_mfma_f32_16x16x32_bf16(Vf1, Pf, A1, 0,0,0);      \
    } while (0)

    #pragma unroll 4
    for (int t = 0; t < 32; ++t) {
        const short8v Kf0 = *(const short8v*)(LBK + t * 2048);
        const short8v Kf1 = *(const short8v*)(LBK + t * 2048 + 1024);
        const short8v Vf0 = *(const short8v*)(LBV + t * 2048);
        const short8v Vf1 = *(const short8v*)(LBV + t * 2048 + 1024);
        QSTEP(QfA, aA0, aA1, lsA);
        QSTEP(QfB, aB0, aB1, lsB);
        QSTEP(QfC, aC0, aC1, lsC);
        QSTEP(QfD, aD0, aD1, lsD);
    }
#undef QSTEP

    lsA += __shfl_xor(lsA, 16); lsA += __shfl_xor(lsA, 32);
    lsB += __shfl_xor(lsB, 16); lsB += __shfl_xor(lsB, 32);
    lsC += __shfl_xor(lsC, 16); lsC += __shfl_xor(lsC, 32);
    lsD += __shfl_xor(lsD, 16); lsD += __shfl_xor(lsD, 32);
    const int bI = head >> 3, hh = head & 7;
    short* op = O + ((size_t)(bI * 1024 + q0w + lq)) * 256 + hh * 32 + g * 4;
#define QOUT(A0, A1, LS, ROFF) do {                                            \
        const float inv = 1.f / (LS);                                          \
        short4v o0 = {bf16rne(A0[0] * inv), bf16rne(A0[1] * inv),              \
                      bf16rne(A0[2] * inv), bf16rne(A0[3] * inv)};             \
        short4v o1 = {bf16rne(A1[0] * inv), bf16rne(A1[1] * inv),              \
                      bf16rne(A1[2] * inv), bf16rne(A1[3] * inv)};             \
        *(short4v*)(op + (ROFF) * 256) = o0;                                   \
        *(short4v*)(op + (ROFF) * 256 + 16) = o1;                              \
    } while (0)
    QOUT(aA0, aA1, lsA, 0);
    QOUT(aB0, aB1, lsB, 16);
    QOUT(aC0, aC1, lsC, 32);
    QOUT(aD0, aD1, lsD, 48);
#undef QOUT
}

// ------------------------------------------------------------ launch
extern "C" void kernel_launch(void* const* d_in, const int* in_sizes, int n_in,
                              void* d_out, int out_size, void* d_ws, size_t ws_size,
                              hipStream_t stream)
{
    const float* obs  = (const float*)d_in[0];
    const float* act  = (const float*)d_in[1];
    const float* inW  = (const float*)d_in[2];
    const float* inb  = (const float*)d_in[3];
    const float* qW   = (const float*)d_in[4];
    const float* qb   = (const float*)d_in[5];
    const float* kW   = (const float*)d_in[6];
    const float* kb   = (const float*)d_in[7];
    const float* vW   = (const float*)d_in[8];
    const float* vb   = (const float*)d_in[9];
    const float* oW   = (const float*)d_in[10];
    const float* ob   = (const float*)d_in[11];
    const float* outW = (const float*)d_in[12];
    const float* outb = (const float*)d_in[13];
    const float* lng  = (const float*)d_in[14];
    const float* lnb  = (const float*)d_in[15];
    float* outp = (float*)d_out;

    const size_t MD = (size_t)M_ * D_;
    float* xF    = (float*)d_ws;
    short* xB    = (short*)(xF + MD);
    short* xIn   = xB + MD;
    short* Q2    = xIn + MD;             // bf16 (B,H,DH,S)
    short* K2    = Q2 + MD;              // bf16 (B,H,S,DH)
    short* VT    = K2 + MD;              // bf16 (B,H,DH,S), sigma-permuted keys
    short* Obf   = VT + MD;              // bf16 attn out (B,S,D)
    short* WTqkv = Obf + MD;
    short* WTo   = WTqkv + 786432;
    short* WTf   = WTo + 262144;
    short* WTin  = WTf + 65536;
    float* cosT2 = (float*)(WTin + 65536);
    float* sinT2 = cosT2 + 16384;

    preproc_k<<<2400, 256, 0, stream>>>(obs, act, qW, kW, vW, oW, outW, inW,
                                        xIn, WTqkv, WTo, WTf, WTin, cosT2, sinT2);

    gemm_k<2,2><<<dim3(128, 4), 512, 0, stream>>>(xIn, WTin, inb, nullptr, nullptr,
            xF, xB, nullptr, nullptr, nullptr, nullptr, nullptr);

    for (int lay = 0; lay < L_; ++lay) {
        gemm_k<0,4><<<dim3(64, 12), 512, 0, stream>>>(xB, WTqkv + lay * 196608,
                qb + lay * 256, kb + lay * 256, vb + lay * 256,
                nullptr, nullptr, Q2, K2, VT, cosT2, sinT2);
        attn_k<<<256, 512, 0, stream>>>(Q2, K2, VT, Obf);
        gemm_k<1,2><<<dim3(128, 4), 512, 0, stream>>>(Obf, WTo + lay * 65536,
                ob + lay * 256, nullptr, nullptr, xF, xB,
                nullptr, nullptr, nullptr, nullptr, nullptr);
    }

    gemmln_k<<<256, 512, 0, stream>>>(xB, WTf, outb, lng, lnb, outp);
}

// Round 14
// 251.033 us; speedup vs baseline: 1.0366x; 1.0366x over previous
//
#include <hip/hip_runtime.h>
#include <hip/hip_bf16.h>
#include <math.h>

#define B_ 16
#define S_ 1024
#define D_ 256
#define H_ 8
#define L_ 4
#define DH_ 32
#define OBS_ 160
#define ACT_ 96
#define M_ (B_*S_)   // 16384

typedef __attribute__((ext_vector_type(8)))  short short8v;   // 8 bf16
typedef __attribute__((ext_vector_type(4)))  short short4v;   // 4 bf16
typedef __attribute__((ext_vector_type(4)))  float f32x4;
typedef __attribute__((ext_vector_type(4)))  unsigned uint4v;

#define ALPHA_ 0.25507313f   // log2(e)/sqrt(32)

__device__ inline short bf16rne(float x) {
    unsigned u = __builtin_bit_cast(unsigned, x);
    unsigned r = (u + 0x7fffu + ((u >> 16) & 1u)) >> 16;
    return (short)r;
}

#if __has_builtin(__builtin_amdgcn_exp2f)
#define EXP2F(x) __builtin_amdgcn_exp2f(x)
#else
#define EXP2F(x) exp2f(x)
#endif

__device__ inline unsigned cvtpk_bf16(float lo, float hi) {
    unsigned r;
    asm("v_cvt_pk_bf16_f32 %0, %1, %2" : "=v"(r) : "v"(lo), "v"(hi));
    return r;
}

// ------------------------------------------------------------ fused preproc
// blocks [0,288): weight cvt+transpose (18 matrices x 16 tiles)
// blocks [288,2336): input concat+cvt (2048)
// blocks [2336,2400): rope table (64)
__global__ __launch_bounds__(256) void preproc_k(
    const float* __restrict__ obs, const float* __restrict__ act,
    const float* __restrict__ qW, const float* __restrict__ kW,
    const float* __restrict__ vW, const float* __restrict__ oW,
    const float* __restrict__ outW, const float* __restrict__ inW,
    short* __restrict__ xIn,
    short* __restrict__ WTqkv, short* __restrict__ WTo,
    short* __restrict__ WTf, short* __restrict__ WTin,
    float* __restrict__ cosT2, float* __restrict__ sinT2)
{
    __shared__ float T[64][65];
    const int bid = blockIdx.x;
    const int tid = threadIdx.x;

    if (bid < 288) {
        const int bx = bid & 15, z = bid >> 4;   // z = 0..17
        const int tr = (bx & 3) * 64, tc = (bx >> 2) * 64;
        const float* src;
        short* dst;
        if (z < 16) {
            int lay = z >> 2, w = z & 3;
            if (w == 0)      { src = qW + lay * 65536; dst = WTqkv + lay * 196608; }
            else if (w == 1) { src = kW + lay * 65536; dst = WTqkv + lay * 196608 + 65536; }
            else if (w == 2) { src = vW + lay * 65536; dst = WTqkv + lay * 196608 + 131072; }
            else             { src = oW + lay * 65536; dst = WTo + lay * 65536; }
        } else if (z == 16) { src = outW; dst = WTf; }
        else                { src = inW;  dst = WTin; }
        #pragma unroll
        for (int it = 0; it < 4; ++it) {
            int r = (tid >> 4) + it * 16, c = (tid & 15) * 4;
            *(float4*)&T[r][c] = *(const float4*)&src[(size_t)(tr + r) * 256 + tc + c];
        }
        __syncthreads();
        #pragma unroll
        for (int it = 0; it < 4; ++it) {
            int n = (tid >> 4) + it * 16, k = (tid & 15) * 4;
            short4v o = {bf16rne(T[k][n]), bf16rne(T[k + 1][n]),
                         bf16rne(T[k + 2][n]), bf16rne(T[k + 3][n])};
            *(short4v*)&dst[(size_t)(tc + n) * 256 + tr + k] = o;
        }
    } else if (bid < 2336) {
        const int idx = ((bid - 288) * 256 + tid) * 8;
        const int row = idx >> 8, col = idx & 255;
        const float* s = (col < OBS_) ? (obs + (size_t)row * OBS_ + col)
                                      : (act + (size_t)row * ACT_ + (col - OBS_));
        const float4 v0 = *(const float4*)s;
        const float4 v1 = *(const float4*)(s + 4);
        short8v o = {bf16rne(v0.x), bf16rne(v0.y), bf16rne(v0.z), bf16rne(v0.w),
                     bf16rne(v1.x), bf16rne(v1.y), bf16rne(v1.z), bf16rne(v1.w)};
        *(short8v*)&xIn[idx] = o;
    } else {
        const int idx = (bid - 2336) * 256 + tid;   // 16384
        const int i = idx >> 10, s = idx & 1023;
        float invf = powf(10000.0f, -(float)(2 * i) / 32.0f);
        float ang = (float)s * invf;
        float sn, cs;
        sincosf(ang, &sn, &cs);
        cosT2[idx] = cs;
        sinT2[idx] = sn;
    }
}

// ------------------------------------------------------------ MFMA GEMM
// BM = IB*64 (IB=4: 256 rows for QKV; IB=2: 128 rows for N=256 GEMMs).
// BN=64, BK=32, 8 waves, reg-staged double-buffered LDS.
// Grid = (rows, cols): row-panel blocks share an XCD.
// EPI 0 (IB=4): QKV fused (N=768): Q -> *ALPHA,rope -> (B,H,DH,S) direct;
//        K -> rope -> (B,H,S,DH) via LDS bounce; V -> (B,H,DH,S) sigma-keys.
// EPI 1: + residual xF -> xF(f32) + xB(bf16)
// EPI 2: -> xF + xB
template<int EPI, int IB>
__global__ __launch_bounds__(512, 4) void gemm_k(
    const short* __restrict__ A, const short* __restrict__ WT,
    const float* __restrict__ bq, const float* __restrict__ bk,
    const float* __restrict__ bv,
    float* __restrict__ xF, short* __restrict__ xB,
    short* __restrict__ Q2, short* __restrict__ K2, short* __restrict__ VT,
    const float* __restrict__ cosT2, const float* __restrict__ sinT2)
{
    __shared__ short As[2][256 * 32];
    __shared__ short Bs[2][64 * 32];
    const int tid = threadIdx.x;          // 0..511
    const int l = tid & 63;
    const int wid = tid >> 6;             // 0..7
    const int wr = wid >> 1, wc = wid & 1;
    const int bm = blockIdx.x * (IB * 64), bn = blockIdx.y * 64;

    const short* aSrc0 = A + (size_t)(bm + (tid >> 2)) * 256 + (tid & 3) * 8;
    const short* aSrc1 = aSrc0 + 128 * 256;
    const short* bSrc  = WT + (size_t)(bn + ((tid & 255) >> 2)) * 256 + (tid & 3) * 8;

    {
        short8v a0 = *(const short8v*)aSrc0;
        *(short8v*)&As[0][tid * 8] = a0;
        if (IB == 4) {
            short8v a1 = *(const short8v*)aSrc1;
            *(short8v*)&As[0][(tid + 512) * 8] = a1;
        }
        if (tid < 256) {
            short8v b0 = *(const short8v*)bSrc;
            *(short8v*)&Bs[0][tid * 8] = b0;
        }
    }
    __syncthreads();

    f32x4 acc[IB][2];
    #pragma unroll
    for (int i = 0; i < IB; ++i)
        #pragma unroll
        for (int j = 0; j < 2; ++j) acc[i][j] = (f32x4){0.f, 0.f, 0.f, 0.f};

    #pragma unroll
    for (int t = 0; t < 8; ++t) {
        const int cur = t & 1;
        short8v na0, na1, nb;
        if (t < 7) {                    // issue next-tile loads before MFMA
            const int k = (t + 1) * 32;
            na0 = *(const short8v*)&aSrc0[k];
            if (IB == 4) na1 = *(const short8v*)&aSrc1[k];
            if (tid < 256) nb = *(const short8v*)&bSrc[k];
        }
        short8v af[IB], bf[2];
        #pragma unroll
        for (int i = 0; i < IB; ++i)
            af[i] = *(const short8v*)&As[cur][(wr * (IB * 16) + i * 16 + (l & 15)) * 32 + (l >> 4) * 8];
        #pragma unroll
        for (int j = 0; j < 2; ++j)
            bf[j] = *(const short8v*)&Bs[cur][(wc * 32 + j * 16 + (l & 15)) * 32 + (l >> 4) * 8];
        #pragma unroll
        for (int i = 0; i < IB; ++i)
            #pragma unroll
            for (int j = 0; j < 2; ++j)
                acc[i][j] = __builtin_amdgcn_mfma_f32_16x16x32_bf16(af[i], bf[j], acc[i][j], 0, 0, 0);
        if (t < 7) {
            const int nxt = cur ^ 1;
            *(short8v*)&As[nxt][tid * 8] = na0;
            if (IB == 4) *(short8v*)&As[nxt][(tid + 512) * 8] = na1;
            if (tid < 256) *(short8v*)&Bs[nxt][tid * 8] = nb;
            __syncthreads();
        }
    }

    if (EPI == 0) {
        const int region = bn >> 8;     // 0=Q 1=K 2=V (uniform per block)
        if (region != 1) {
            // Q and V: direct (B,H,DH,S) stores. V adds sigma key-perm;
            // Q adds ALPHA scale + rope.
            #pragma unroll
            for (int i = 0; i < IB; ++i) {
                const int m0 = bm + wr * (IB * 16) + i * 16 + ((l >> 4) << 2);
                const int bI = m0 >> 10, s0 = m0 & 1023;
                int sp = s0;
                if (region == 2) {
                    // sigma: key<16 -> 8*(key>>2)+(key&3); key>=16 -> +4
                    const int w = s0 & 31;
                    sp = (s0 & ~31) | ((((w & 15) >> 2) << 3) | ((w >> 4) << 2));
                }
                #pragma unroll
                for (int j = 0; j < 2; ++j) {
                    const int nl = (bn & 255) + wc * 32 + j * 16 + (l & 15);
                    const float bb = (region == 2) ? bv[nl] : bq[nl];
                    f32x4 v = acc[i][j];
                    v[0] += bb; v[1] += bb; v[2] += bb; v[3] += bb;
                    if (region == 0) {
                        v *= ALPHA_;
                        const int ir = (nl & 31) >> 1;
                        const f32x4 cs = *(const f32x4*)&cosT2[ir * 1024 + s0];
                        const f32x4 sn = *(const f32x4*)&sinT2[ir * 1024 + s0];
                        f32x4 pr;
                        #pragma unroll
                        for (int c = 0; c < 4; ++c) pr[c] = __shfl_xor(v[c], 1);
                        const float sg = (nl & 1) ? 1.f : -1.f;
                        #pragma unroll
                        for (int c = 0; c < 4; ++c)
                            v[c] = v[c] * cs[c] + sg * pr[c] * sn[c];
                    }
                    const int h = nl >> 5, dhh = nl & 31;
                    short4v o = {bf16rne(v[0]), bf16rne(v[1]),
                                 bf16rne(v[2]), bf16rne(v[3])};
                    short* dst = (region == 2) ? VT : Q2;
                    *(short4v*)&dst[((size_t)((bI * 8 + h) * 32 + dhh) << 10) + sp] = o;
                }
            }
        } else {
            // K: bias + rope, bounce via LDS -> (B,H,S,DH)
            __syncthreads();
            short* scr = &As[0][0];   // 256 x 64 bf16, chunk-XOR swizzled
            #pragma unroll
            for (int i = 0; i < IB; ++i) {
                const int tl0 = wr * (IB * 16) + i * 16 + ((l >> 4) << 2);
                const int s0r = (bm + tl0) & 1023;
                #pragma unroll
                for (int j = 0; j < 2; ++j) {
                    const int ncl = wc * 32 + j * 16 + (l & 15);
                    const int nl = (bn & 255) + ncl;
                    const float bb = bk[nl];
                    f32x4 v = acc[i][j];
                    v[0] += bb; v[1] += bb; v[2] += bb; v[3] += bb;
                    const int ir = (nl & 31) >> 1;
                    const f32x4 cs = *(const f32x4*)&cosT2[ir * 1024 + s0r];
                    const f32x4 sn = *(const f32x4*)&sinT2[ir * 1024 + s0r];
                    f32x4 pr;
                    #pragma unroll
                    for (int c = 0; c < 4; ++c) pr[c] = __shfl_xor(v[c], 1);
                    const float sg = (nl & 1) ? 1.f : -1.f;
                    #pragma unroll
                    for (int c = 0; c < 4; ++c)
                        v[c] = v[c] * cs[c] + sg * pr[c] * sn[c];
                    #pragma unroll
                    for (int c = 0; c < 4; ++c) {
                        const int tl = tl0 + c;
                        const int pos = (((ncl >> 3) ^ (tl & 7)) << 3) | (ncl & 7);
                        scr[tl * 64 + pos] = bf16rne(v[c]);
                    }
                }
            }
            __syncthreads();
            const int r = tid >> 1, h2 = tid & 1;   // r: 0..255
            const int tok = bm + r;
            const int bI = tok >> 10, s0 = tok & 1023;
            const int hh = ((bn & 255) >> 5) + h2;
            short* dst = K2 + ((size_t)((bI * 8 + hh) * 1024 + s0)) * 32;
            #pragma unroll
            for (int k = 0; k < 4; ++k) {
                const int pos = ((h2 * 4 + k) ^ (r & 7)) << 3;
                *(uint4*)&dst[k * 8] = *(const uint4*)&scr[r * 64 + pos];
            }
        }
    } else {
        #pragma unroll
        for (int i = 0; i < IB; ++i) {
            const int m0 = bm + wr * (IB * 16) + i * 16 + ((l >> 4) << 2);
            #pragma unroll
            for (int j = 0; j < 2; ++j) {
                const int nn = bn + wc * 32 + j * 16 + (l & 15);
                const float bb = bq[nn];
                const f32x4 v = acc[i][j];
                #pragma unroll
                for (int c = 0; c < 4; ++c) {
                    float rr = v[c] + bb;
                    const size_t off = (size_t)(m0 + c) * 256 + nn;
                    if (EPI == 1) rr += xF[off];
                    xF[off] = rr;
                    xB[off] = bf16rne(rr);
                }
            }
        }
    }
}

// ------------------------------------------------------------ fused out-GEMM + LayerNorm
// BM=64, BN=256 (full rows per block), grid 256 blocks, 512 threads.
// Wave tile 16 rows x 128 cols (wr2 = wid>>1 row-group, wc2 = wid&1 col-half).
// LN: per-lane partials -> 4x shfl_xor over lq -> 1KB LDS cross-wave-pair.
__global__ __launch_bounds__(512, 2) void gemmln_k(
    const short* __restrict__ A, const short* __restrict__ WT,
    const float* __restrict__ outb, const float* __restrict__ lng,
    const float* __restrict__ lnb, float* __restrict__ outp)
{
    __shared__ short As[2][64 * 32];
    __shared__ short Bs[2][256 * 32];
    __shared__ float red[64][2][2];     // [row][col-half][stat]
    const int tid = threadIdx.x;
    const int l = tid & 63;
    const int wid = tid >> 6;
    const int wr2 = wid >> 1, wc2 = wid & 1;
    const int lq = l & 15, g = l >> 4;
    const int bm = blockIdx.x * 64;

    const short* aSrc  = A + (size_t)(bm + ((tid & 255) >> 2)) * 256 + (tid & 3) * 8;
    const short* bSrc0 = WT + (size_t)(tid >> 2) * 256 + (tid & 3) * 8;
    const short* bSrc1 = bSrc0 + (size_t)128 * 256;

    if (tid < 256) *(short8v*)&As[0][tid * 8] = *(const short8v*)aSrc;
    *(short8v*)&Bs[0][tid * 8]         = *(const short8v*)bSrc0;
    *(short8v*)&Bs[0][(tid + 512) * 8] = *(const short8v*)bSrc1;
    __syncthreads();

    f32x4 acc[8];
    #pragma unroll
    for (int j = 0; j < 8; ++j) acc[j] = (f32x4){0.f, 0.f, 0.f, 0.f};

    #pragma unroll
    for (int t = 0; t < 8; ++t) {
        const int cur = t & 1;
        short8v na, nb0, nb1;
        if (t < 7) {
            const int k = (t + 1) * 32;
            if (tid < 256) na = *(const short8v*)&aSrc[k];
            nb0 = *(const short8v*)&bSrc0[k];
            nb1 = *(const short8v*)&bSrc1[k];
        }
        const short8v af = *(const short8v*)&As[cur][(wr2 * 16 + lq) * 32 + g * 8];
        short8v bf[8];
        #pragma unroll
        for (int j = 0; j < 8; ++j)
            bf[j] = *(const short8v*)&Bs[cur][(wc2 * 128 + j * 16 + lq) * 32 + g * 8];
        #pragma unroll
        for (int j = 0; j < 8; ++j)
            acc[j] = __builtin_amdgcn_mfma_f32_16x16x32_bf16(af, bf[j], acc[j], 0, 0, 0);
        if (t < 7) {
            const int nxt = cur ^ 1;
            if (tid < 256) *(short8v*)&As[nxt][tid * 8] = na;
            *(short8v*)&Bs[nxt][tid * 8]         = nb0;
            *(short8v*)&Bs[nxt][(tid + 512) * 8] = nb1;
            __syncthreads();
        }
    }

    // bias + LN partials
    float rs[4] = {0.f, 0.f, 0.f, 0.f}, rq[4] = {0.f, 0.f, 0.f, 0.f};
    #pragma unroll
    for (int j = 0; j < 8; ++j) {
        const float bb = outb[wc2 * 128 + j * 16 + lq];
        #pragma unroll
        for (int c = 0; c < 4; ++c) {
            float v = acc[j][c] + bb;
            acc[j][c] = v;
            rs[c] += v;
            rq[c] += v * v;
        }
    }
    #pragma unroll
    for (int off = 1; off <= 8; off <<= 1) {
        #pragma unroll
        for (int c = 0; c < 4; ++c) {
            rs[c] += __shfl_xor(rs[c], off);
            rq[c] += __shfl_xor(rq[c], off);
        }
    }
    if (lq == 0) {
        #pragma unroll
        for (int c = 0; c < 4; ++c) {
            red[wr2 * 16 + g * 4 + c][wc2][0] = rs[c];
            red[wr2 * 16 + g * 4 + c][wc2][1] = rq[c];
        }
    }
    __syncthreads();
    float mean[4], rstd[4];
    #pragma unroll
    for (int c = 0; c < 4; ++c) {
        const int row = wr2 * 16 + g * 4 + c;
        const float sT = red[row][0][0] + red[row][1][0];
        const float qT = red[row][0][1] + red[row][1][1];
        mean[c] = sT * (1.f / 256.f);
        const float var = qT * (1.f / 256.f) - mean[c] * mean[c];
        rstd[c] = rsqrtf(var + 1e-5f);
    }
    float* seq = outp + B_ * D_;
    #pragma unroll
    for (int j = 0; j < 8; ++j) {
        const int col = wc2 * 128 + j * 16 + lq;
        const float gv = lng[col], bvv = lnb[col];
        #pragma unroll
        for (int c = 0; c < 4; ++c) {
            const int grow = bm + wr2 * 16 + g * 4 + c;
            const float o = (acc[j][c] - mean[c]) * rstd[c] * gv + bvv;
            seq[(size_t)grow * 256 + col] = o;
            if ((grow & (S_ - 1)) == S_ - 1)
                outp[(size_t)(grow >> 10) * 256 + col] = o;
        }
    }
}

// ------------------------------------------------------------ Attention
// Q2: bf16 (B,H,DH,S) (pre-scaled by log2e/sqrt(DH), rope'd)
// K2: bf16 (B,H,S,DH) (rope'd)
// VT: bf16 (B,H,DH,S), key order sigma-permuted per 32-block
// O:  bf16 (B,S,D)
// Block = 1 head x 512 q (8 waves x 64 q). Whole K+V staged to static
// 128 KiB LDS once; ONE barrier; 32-step barrier-free loop. lsum computed
// on the MFMA pipe via an all-ones A-fragment (VALU is the bottleneck;
// matrix pipe has 5x headroom) — R12-verified.
__global__ __launch_bounds__(512, 2) void attn_k(
    const short* __restrict__ Q2, const short* __restrict__ K2,
    const short* __restrict__ VT, short* __restrict__ O)
{
    __shared__ short lb[65536];          // 131072 B static LDS
    const int tid = threadIdx.x;
    const int l = tid & 63, wid = tid >> 6;
    const int head = blockIdx.x & 127;   // b*8+h; bid%8 = head%8 -> XCD-pinned
    const int qh = blockIdx.x >> 7;      // 0..1
    const int q0w = qh * 512 + wid * 64;
    const int lq = l & 15, g = l >> 4;

    const short* Kh = K2 + (size_t)head * 32768;
    const short* Vh = VT + (size_t)head * 32768;

    // -------- stage all of K and V (64 KB each), swizzled tiles
    #pragma unroll
    for (int i = 0; i < 8; ++i) {
        const int c = tid + i * 512;           // 16B chunk id, 0..4095
        short8v kv = *(const short8v*)(Kh + c * 8);
        const int key = c >> 2, dc = c & 3;
        *(short8v*)((char*)lb + key * 64 + ((dc ^ ((key >> 1) & 3)) << 4)) = kv;
        short8v vv = *(const short8v*)(Vh + c * 8);
        const int dh = c >> 7, kc = c & 127;
        *(short8v*)((char*)lb + 65536 + (kc >> 2) * 2048 + dh * 64
                    + (((kc & 3) ^ ((dh >> 1) & 3)) << 4)) = vv;
    }

    // Q fragments from (B,H,DH,S): one-time strided loads
    const short* qbase = Q2 + (size_t)head * 32768 + q0w + lq;
    short8v QfA, QfB, QfC, QfD;
    #pragma unroll
    for (int j = 0; j < 8; ++j) {
        const size_t off = (size_t)(g * 8 + j) * 1024;
        QfA[j] = qbase[off];
        QfB[j] = qbase[off + 16];
        QfC[j] = qbase[off + 32];
        QfD[j] = qbase[off + 48];
    }
    const short one = (short)0x3F80;
    const short8v OnesF = {one, one, one, one, one, one, one, one};

    const char* LBK = (const char*)lb + lq * 64 + ((g ^ ((lq >> 1) & 3)) << 4);
    const char* LBV = LBK + 65536;

    f32x4 aA0 = {0.f,0.f,0.f,0.f}, aA1 = {0.f,0.f,0.f,0.f};
    f32x4 aB0 = {0.f,0.f,0.f,0.f}, aB1 = {0.f,0.f,0.f,0.f};
    f32x4 aC0 = {0.f,0.f,0.f,0.f}, aC1 = {0.f,0.f,0.f,0.f};
    f32x4 aD0 = {0.f,0.f,0.f,0.f}, aD1 = {0.f,0.f,0.f,0.f};
    f32x4 lA = {0.f,0.f,0.f,0.f}, lB = {0.f,0.f,0.f,0.f};
    f32x4 lC = {0.f,0.f,0.f,0.f}, lD = {0.f,0.f,0.f,0.f};
    const f32x4 z4 = {0.f, 0.f, 0.f, 0.f};

    __syncthreads();                      // the ONLY barrier

#define QSTEP(QF, A0, A1, LACC) do {                                           \
        f32x4 s0 = __builtin_amdgcn_mfma_f32_16x16x32_bf16(Kf0, QF, z4, 0,0,0);\
        f32x4 s1 = __builtin_amdgcn_mfma_f32_16x16x32_bf16(Kf1, QF, z4, 0,0,0);\
        float p0 = EXP2F(s0[0]), p1 = EXP2F(s0[1]);                            \
        float p2 = EXP2F(s0[2]), p3 = EXP2F(s0[3]);                            \
        float p4 = EXP2F(s1[0]), p5 = EXP2F(s1[1]);                            \
        float p6 = EXP2F(s1[2]), p7 = EXP2F(s1[3]);                            \
        uint4v pv = {cvtpk_bf16(p0, p1), cvtpk_bf16(p2, p3),                   \
                     cvtpk_bf16(p4, p5), cvtpk_bf16(p6, p7)};                  \
        short8v Pf = __builtin_bit_cast(short8v, pv);                          \
        A0 = __builtin_amdgcn_mfma_f32_16x16x32_bf16(Vf0, Pf, A0, 0,0,0);      \
        A1 = __builtin_amdgcn_mfma_f32_16x16x32_bf16(Vf1, Pf, A1, 0,0,0);      \
        LACC = __builtin_amdgcn_mfma_f32_16x16x32_bf16(OnesF, Pf, LACC, 0,0,0);\
    } while (0)

    #pragma unroll 4
    for (int t = 0; t < 32; ++t) {
        const short8v Kf0 = *(const short8v*)(LBK + t * 2048);
        const short8v Kf1 = *(const short8v*)(LBK + t * 2048 + 1024);
        const short8v Vf0 = *(const short8v*)(LBV + t * 2048);
        const short8v Vf1 = *(const short8v*)(LBV + t * 2048 + 1024);
        QSTEP(QfA, aA0, aA1, lA);
        QSTEP(QfB, aB0, aB1, lB);
        QSTEP(QfC, aC0, aC1, lC);
        QSTEP(QfD, aD0, aD1, lD);
    }
#undef QSTEP

    const int bI = head >> 3, hh = head & 7;
    short* op = O + ((size_t)(bI * 1024 + q0w + lq)) * 256 + hh * 32 + g * 4;
#define QOUT(A0, A1, LACC, ROFF) do {                                          \
        const float inv = 1.f / (LACC)[0];                                     \
        short4v o0 = {bf16rne(A0[0] * inv), bf16rne(A0[1] * inv),              \
                      bf16rne(A0[2] * inv), bf16rne(A0[3] * inv)};             \
        short4v o1 = {bf16rne(A1[0] * inv), bf16rne(A1[1] * inv),              \
                      bf16rne(A1[2] * inv), bf16rne(A1[3] * inv)};             \
        *(short4v*)(op + (ROFF) * 256) = o0;                                   \
        *(short4v*)(op + (ROFF) * 256 + 16) = o1;                              \
    } while (0)
    QOUT(aA0, aA1, lA, 0);
    QOUT(aB0, aB1, lB, 16);
    QOUT(aC0, aC1, lC, 32);
    QOUT(aD0, aD1, lD, 48);
#undef QOUT
}

// ------------------------------------------------------------ launch
extern "C" void kernel_launch(void* const* d_in, const int* in_sizes, int n_in,
                              void* d_out, int out_size, void* d_ws, size_t ws_size,
                              hipStream_t stream)
{
    const float* obs  = (const float*)d_in[0];
    const float* act  = (const float*)d_in[1];
    const float* inW  = (const float*)d_in[2];
    const float* inb  = (const float*)d_in[3];
    const float* qW   = (const float*)d_in[4];
    const float* qb   = (const float*)d_in[5];
    const float* kW   = (const float*)d_in[6];
    const float* kb   = (const float*)d_in[7];
    const float* vW   = (const float*)d_in[8];
    const float* vb   = (const float*)d_in[9];
    const float* oW   = (const float*)d_in[10];
    const float* ob   = (const float*)d_in[11];
    const float* outW = (const float*)d_in[12];
    const float* outb = (const float*)d_in[13];
    const float* lng  = (const float*)d_in[14];
    const float* lnb  = (const float*)d_in[15];
    float* outp = (float*)d_out;

    const size_t MD = (size_t)M_ * D_;
    float* xF    = (float*)d_ws;
    short* xB    = (short*)(xF + MD);
    short* xIn   = xB + MD;
    short* Q2    = xIn + MD;             // bf16 (B,H,DH,S)
    short* K2    = Q2 + MD;              // bf16 (B,H,S,DH)
    short* VT    = K2 + MD;              // bf16 (B,H,DH,S), sigma-permuted keys
    short* Obf   = VT + MD;              // bf16 attn out (B,S,D)
    short* WTqkv = Obf + MD;
    short* WTo   = WTqkv + 786432;
    short* WTf   = WTo + 262144;
    short* WTin  = WTf + 65536;
    float* cosT2 = (float*)(WTin + 65536);
    float* sinT2 = cosT2 + 16384;

    preproc_k<<<2400, 256, 0, stream>>>(obs, act, qW, kW, vW, oW, outW, inW,
                                        xIn, WTqkv, WTo, WTf, WTin, cosT2, sinT2);

    gemm_k<2,2><<<dim3(128, 4), 512, 0, stream>>>(xIn, WTin, inb, nullptr, nullptr,
            xF, xB, nullptr, nullptr, nullptr, nullptr, nullptr);

    for (int lay = 0; lay < L_; ++lay) {
        gemm_k<0,4><<<dim3(64, 12), 512, 0, stream>>>(xB, WTqkv + lay * 196608,
                qb + lay * 256, kb + lay * 256, vb + lay * 256,
                nullptr, nullptr, Q2, K2, VT, cosT2, sinT2);
        attn_k<<<256, 512, 0, stream>>>(Q2, K2, VT, Obf);
        gemm_k<1,2><<<dim3(128, 4), 512, 0, stream>>>(Obf, WTo + lay * 65536,
                ob + lay * 256, nullptr, nullptr, xF, xB,
                nullptr, nullptr, nullptr, nullptr, nullptr);
    }

    gemmln_k<<<256, 512, 0, stream>>>(xB, WTf, outb, lng, lnb, outp);
}